// Round 5
// baseline (291.185 us; speedup 1.0000x reference)
//
#include <hip/hip_runtime.h>
#include <hip/hip_bf16.h>

typedef __attribute__((ext_vector_type(8))) __bf16 bf16x8;
typedef __attribute__((ext_vector_type(16))) float f32x16;

#define SCALE_L2E 14.4269504088896f // 10 * log2(e)
#define NTOT 32768

#define AS_GLOBAL __attribute__((address_space(1)))
#define AS_LDS    __attribute__((address_space(3)))

__device__ inline void async_copy16(const void* g, void* l) {
    __builtin_amdgcn_global_load_lds((const AS_GLOBAL void*)g, (AS_LDS void*)l, 16, 0, 0);
}

// ---------------------------------------------------------------------------
// bf16 pack helpers (RNE)
// ---------------------------------------------------------------------------
__device__ inline unsigned int f2bf(float f) {
    unsigned int u = __builtin_bit_cast(unsigned int, f);
    u += 0x7fffu + ((u >> 16) & 1u);
    return u >> 16;
}

__device__ inline uint4 pack8(float4 x, float4 y, float s) {
    uint4 r;
    r.x = f2bf(x.x * s) | (f2bf(x.y * s) << 16);
    r.y = f2bf(x.z * s) | (f2bf(x.w * s) << 16);
    r.z = f2bf(y.x * s) | (f2bf(y.y * s) << 16);
    r.w = f2bf(y.z * s) | (f2bf(y.w * s) << 16);
    return r;
}

__device__ inline float dot8(float4 x, float4 y) {
    return x.x*y.x + x.y*y.y + x.z*y.z + x.w*y.w;
}

// ---------------------------------------------------------------------------
// Kernel 1: L2-normalize -> bf16 FRAGMENT-MAJOR + fp32 diag partials.
// E1 is PRE-SCALED by 10*log2(e) so gemm's epilogue is exp2(acc - c).
// All 16 row-pair loads issued up front (256 B/lane in flight -> HBM-bound).
// Grid 1024 x 256. Also inits scalars/counter for fin (ws is poisoned).
// ---------------------------------------------------------------------------
__global__ __launch_bounds__(256) void nrm_kernel(
        const float* __restrict__ A, const float* __restrict__ B,
        uint4* __restrict__ E1f, uint4* __restrict__ E2f,
        float* __restrict__ diagPart, float* __restrict__ scalars,
        unsigned int* __restrict__ counter) {
    const int tid = threadIdx.x, w = tid >> 6, l = tid & 63;
    const int q = l & 31, h = l >> 5;
    const int wid = blockIdx.x * 4 + w;            // 0..4095, 8 rows each

    const float4* A4 = (const float4*)A + ((size_t)wid * 8 + h) * 64 + q * 2;
    const float4* B4 = (const float4*)B + ((size_t)wid * 8 + h) * 64 + q * 2;

    float4 a[8], bb[8];
    #pragma unroll
    for (int i = 0; i < 4; ++i) {                  // all loads up front (MLP)
        a[2*i]    = A4[i * 128];
        a[2*i+1]  = A4[i * 128 + 1];
        bb[2*i]   = B4[i * 128];
        bb[2*i+1] = B4[i * 128 + 1];
    }

    float ddAcc = 0.f;
    #pragma unroll
    for (int i = 0; i < 4; ++i) {
        float sa = dot8(a[2*i], a[2*i]) + dot8(a[2*i+1], a[2*i+1]);
        float sb = dot8(bb[2*i], bb[2*i]) + dot8(bb[2*i+1], bb[2*i+1]);
        float dd = dot8(a[2*i], bb[2*i]) + dot8(a[2*i+1], bb[2*i+1]);
        #pragma unroll
        for (int off = 1; off <= 16; off <<= 1) {
            sa += __shfl_xor(sa, off);
            sb += __shfl_xor(sb, off);
            dd += __shfl_xor(dd, off);
        }
        const float ia = 1.0f / fmaxf(sqrtf(sa), 1e-12f);
        const float ib = 1.0f / fmaxf(sqrtf(sb), 1e-12f);
        if (q == 0) ddAcc += dd * ia * ib * 10.0f;

        const int n0 = wid * 8 + i * 2 + h;
        const size_t chunk = (size_t)(n0 >> 11) * 65536
                           + (size_t)((n0 & 2047) >> 5) * 1024
                           + (q >> 1) * 64 + (q & 1) * 32 + (n0 & 31);
        E1f[chunk] = pack8(a[2*i], a[2*i+1], ia * SCALE_L2E);  // pre-scaled
        E2f[chunk] = pack8(bb[2*i], bb[2*i+1], ib);
    }

    #pragma unroll
    for (int off = 1; off <= 32; off <<= 1) ddAcc += __shfl_xor(ddAcc, off);
    __shared__ float part[4];
    if (l == 0) part[w] = ddAcc;
    __syncthreads();
    if (tid == 0) diagPart[blockIdx.x] = part[0] + part[1] + part[2] + part[3];
    if (blockIdx.x == 0 && tid == 0) { scalars[0] = 0.f; *counter = 0u; }
}

// ---------------------------------------------------------------------------
// Kernel 2: fused GEMM + exp + row/col partials. 512 blocks, 4 waves.
// Block: 256 rows x 512 cols; wave: 64 rows (af0/af1 in regs) x 512 cols.
// B staged 32-cols (16 KB) via global_load_lds, TRIPLE-buffered, staged 2
// ahead; K-loop uses raw s_waitcnt vmcnt(4) + s_barrier (no vmcnt(0) drain).
// blockIdx: rt = idx>>6 so the 8 blocks sharing one B stream hit one XCD.
// ---------------------------------------------------------------------------
__global__ __launch_bounds__(256, 2) void gemm_kernel(
        const bf16x8* __restrict__ E1f, const uint4* __restrict__ E2f,
        float* __restrict__ colPart, float* __restrict__ rowPart) {
    __shared__ bf16x8 Bbuf[3][1024];   // 3 x 16 KB
    __shared__ float colLDS[2048];     // 4 per-wave slices of 512

    const int tid = threadIdx.x, w = tid >> 6, l = tid & 63;
    const int rt = blockIdx.x >> 6;            // 0..7  (same (ct,b) -> same XCD)
    const int ct = (blockIdx.x >> 4) & 3, b = blockIdx.x & 15;

    for (int i = l; i < 512; i += 64) colLDS[w * 512 + i] = 0.f;

    // A fragments: two 32-row tiles (fragment-major, coalesced 1KB loads)
    const bf16x8* Af0 = E1f + (size_t)b * 65536 + (size_t)(rt * 8 + w * 2) * 1024 + l;
    const bf16x8* Af1 = Af0 + 1024;
    bf16x8 af0[16], af1[16];
    #pragma unroll
    for (int kt = 0; kt < 16; ++kt) { af0[kt] = Af0[kt * 64]; af1[kt] = Af1[kt * 64]; }

    float rowAcc0[16], rowAcc1[16];
    #pragma unroll
    for (int r = 0; r < 16; ++r) { rowAcc0[r] = 0.f; rowAcc1[r] = 0.f; }

    const uint4* Bb = E2f + (size_t)b * 65536 + (size_t)ct * 16384 + l;

    // stage col-group cg into Bbuf[buf]; wave w stages kt = w*4 .. w*4+3
    auto stage = [&](int buf, int cg) {
        const uint4* src = Bb + (size_t)cg * 1024 + (w * 4) * 64;
        #pragma unroll
        for (int j = 0; j < 4; ++j)
            async_copy16(src + j * 64, &Bbuf[buf][(w * 4 + j) * 64]);
    };

    stage(0, 0);
    stage(1, 1);

    #pragma unroll
    for (int cg = 0; cg < 16; ++cg) {
        // wait own stage(cg) DMAs (4 newest = stage(cg+1) may remain in flight)
        if (cg < 15) asm volatile("s_waitcnt vmcnt(4)" ::: "memory");
        else         asm volatile("s_waitcnt vmcnt(0)" ::: "memory");
        __builtin_amdgcn_s_barrier();   // all waves' stage(cg) complete
        if (cg < 14) stage((cg + 2) % 3, cg + 2);

        const bf16x8* Bf = Bbuf[cg % 3];
        f32x16 acc0, acc1;
        #pragma unroll
        for (int r = 0; r < 16; ++r) { acc0[r] = 0.f; acc1[r] = 0.f; }

        #pragma unroll
        for (int kt = 0; kt < 16; ++kt) {
            bf16x8 bfrag = Bf[kt * 64 + l];
            acc0 = __builtin_amdgcn_mfma_f32_32x32x16_bf16(af0[kt], bfrag, acc0, 0, 0, 0);
            acc1 = __builtin_amdgcn_mfma_f32_32x32x16_bf16(af1[kt], bfrag, acc1, 0, 0, 0);
        }

        // epilogue: A was pre-scaled -> e = exp2(acc - 10*log2e)
        float p = 0.f;
        #pragma unroll
        for (int r = 0; r < 16; ++r) {
            float e0 = exp2f(acc0[r] - SCALE_L2E);
            float e1 = exp2f(acc1[r] - SCALE_L2E);
            rowAcc0[r] += e0;
            rowAcc1[r] += e1;
            p += e0 + e1;
        }
        p += __shfl_xor(p, 32);                    // fold 16-row halves
        if (l < 32) colLDS[w * 512 + cg * 32 + l] += p;   // wave-private
    }

    // row sums: reduce across 32 column-lanes
    #pragma unroll
    for (int r = 0; r < 16; ++r) {
        #pragma unroll
        for (int off = 1; off <= 16; off <<= 1) {
            rowAcc0[r] += __shfl_xor(rowAcc0[r], off);
            rowAcc1[r] += __shfl_xor(rowAcc1[r], off);
        }
    }
    if ((l & 31) == 0) {
        // C/D layout: row = (r&3) + 8*(r>>2) + 4*(lane>>5); plain stores
        float* rs = rowPart + (size_t)(b * 4 + ct) * 2048 + rt * 256 + w * 64 + 4 * (l >> 5);
        #pragma unroll
        for (int r = 0; r < 16; ++r) {
            const int rl = (r & 3) + 8 * (r >> 2);
            rs[rl]      = rowAcc0[r];
            rs[rl + 32] = rowAcc1[r];
        }
    }

    __syncthreads();   // full barrier before cross-wave colLDS fold
    float* gcol = colPart + (size_t)((b * 4 + ct) * 8 + rt) * 512;
    for (int i = tid; i < 512; i += 256)
        gcol[i] = colLDS[i] + colLDS[512 + i] + colLDS[1024 + i] + colLDS[1536 + i];
}

// ---------------------------------------------------------------------------
// Kernel 3: fold partials, sum logs, last block finalizes.
// 64 blocks x 256. Block: 512 cols (8 rt-partials) + 512 rows (4 ct-partials).
// ---------------------------------------------------------------------------
__global__ __launch_bounds__(256) void fin_kernel(
        const float* __restrict__ colPart, const float* __restrict__ rowPart,
        const float* __restrict__ diagPart, float* __restrict__ scalars,
        unsigned int* __restrict__ counter, float* __restrict__ out) {
    const int tid = threadIdx.x;
    float s = 0.f;
    #pragma unroll
    for (int k = 0; k < 2; ++k) {
        const int g = blockIdx.x * 512 + k * 256 + tid;
        // column g: b = g>>11, ct = (g>>9)&3, c = g&511
        const float* cp = colPart + (size_t)(((g >> 11) * 4 + ((g >> 9) & 3)) * 8) * 512 + (g & 511);
        float cs = 0.f;
        #pragma unroll
        for (int rt = 0; rt < 8; ++rt) cs += cp[rt * 512];
        // row g: b = g>>11, r = g&2047
        const float* rp = rowPart + (size_t)(g >> 11) * 4 * 2048 + (g & 2047);
        float rsum = rp[0] + rp[2048] + rp[4096] + rp[6144];
        s += logf(cs) + logf(rsum);
    }
    #pragma unroll
    for (int off = 1; off <= 32; off <<= 1) s += __shfl_xor(s, off);
    __shared__ float part[4];
    __shared__ unsigned int lastFlag;
    if ((tid & 63) == 0) part[tid >> 6] = s;
    __syncthreads();
    if (tid == 0) {
        atomicAdd(&scalars[0], part[0] + part[1] + part[2] + part[3]);
        __threadfence();
        lastFlag = (atomicAdd(counter, 1u) == 63u) ? 1u : 0u;
    }
    __syncthreads();
    if (lastFlag) {
        float d = diagPart[tid] + diagPart[tid + 256]
                + diagPart[tid + 512] + diagPart[tid + 768];
        #pragma unroll
        for (int off = 1; off <= 32; off <<= 1) d += __shfl_xor(d, off);
        if ((tid & 63) == 0) part[tid >> 6] = d;
        __syncthreads();
        if (tid == 0) {
            const float diag = part[0] + part[1] + part[2] + part[3];
            const float logSum = atomicAdd(&scalars[0], 0.f);  // coherent read
            out[0] = (logSum - 2.0f * diag) / (float)NTOT + 20.0f;
        }
    }
}

// ---------------------------------------------------------------------------
extern "C" void kernel_launch(void* const* d_in, const int* in_sizes, int n_in,
                              void* d_out, int out_size, void* d_ws, size_t ws_size,
                              hipStream_t stream) {
    const float* A = (const float*)d_in[0];
    const float* B = (const float*)d_in[1];

    char* w = (char*)d_ws;
    uint4* E1f = (uint4*)w;                                    // 16 MB
    uint4* E2f = (uint4*)(w + (size_t)16 * 1024 * 1024);       // 16 MB
    float* colPart = (float*)(w + (size_t)32 * 1024 * 1024);   // 262144 f (1 MB)
    float* rowPart = colPart + 262144;                         // 131072 f (0.5 MB)
    float* diagPart = rowPart + 131072;                        // 1024 f
    float* scalars = diagPart + 1024;                          // [logSum]
    unsigned int* counter = (unsigned int*)(scalars + 1);

    hipLaunchKernelGGL(nrm_kernel, dim3(1024), dim3(256), 0, stream,
                       A, B, E1f, E2f, diagPart, scalars, counter);
    hipLaunchKernelGGL(gemm_kernel, dim3(512), dim3(256), 0, stream,
                       (const bf16x8*)E1f, (const uint4*)E2f, colPart, rowPart);
    hipLaunchKernelGGL(fin_kernel, dim3(64), dim3(256), 0, stream,
                       colPart, rowPart, diagPart, scalars, counter, (float*)d_out);
}

// Round 6
// 157.233 us; speedup vs baseline: 1.8519x; 1.8519x over previous
//
#include <hip/hip_runtime.h>
#include <hip/hip_bf16.h>

typedef __attribute__((ext_vector_type(8))) __bf16 bf16x8;
typedef __attribute__((ext_vector_type(16))) float f32x16;

#define SCALE_L2E 14.4269504088896f // 10 * log2(e)
#define NTOT 32768

#define AS_GLOBAL __attribute__((address_space(1)))
#define AS_LDS    __attribute__((address_space(3)))

__device__ inline void async_copy16(const void* g, void* l) {
    __builtin_amdgcn_global_load_lds((const AS_GLOBAL void*)g, (AS_LDS void*)l, 16, 0, 0);
}

// ---------------------------------------------------------------------------
// bf16 pack helpers (RNE)
// ---------------------------------------------------------------------------
__device__ inline unsigned int f2bf(float f) {
    unsigned int u = __builtin_bit_cast(unsigned int, f);
    u += 0x7fffu + ((u >> 16) & 1u);
    return u >> 16;
}

__device__ inline uint4 pack8(float4 x, float4 y, float s) {
    uint4 r;
    r.x = f2bf(x.x * s) | (f2bf(x.y * s) << 16);
    r.y = f2bf(x.z * s) | (f2bf(x.w * s) << 16);
    r.z = f2bf(y.x * s) | (f2bf(y.y * s) << 16);
    r.w = f2bf(y.z * s) | (f2bf(y.w * s) << 16);
    return r;
}

__device__ inline float dot8(float4 x, float4 y) {
    return x.x*y.x + x.y*y.y + x.z*y.z + x.w*y.w;
}

// ---------------------------------------------------------------------------
// Kernel 1: L2-normalize -> bf16 FRAGMENT-MAJOR + fp32 diag partials.
// E1 is PRE-SCALED by 10*log2(e) so gemm's epilogue is exp2(acc - c).
// All 16 row-pair loads issued up front (256 B/lane in flight).
// Grid 1024 x 256. Also inits scalars/counter for fin (ws is poisoned).
// ---------------------------------------------------------------------------
__global__ __launch_bounds__(256) void nrm_kernel(
        const float* __restrict__ A, const float* __restrict__ B,
        uint4* __restrict__ E1f, uint4* __restrict__ E2f,
        float* __restrict__ diagPart, float* __restrict__ scalars,
        unsigned int* __restrict__ counter) {
    const int tid = threadIdx.x, w = tid >> 6, l = tid & 63;
    const int q = l & 31, h = l >> 5;
    const int wid = blockIdx.x * 4 + w;            // 0..4095, 8 rows each

    const float4* A4 = (const float4*)A + ((size_t)wid * 8 + h) * 64 + q * 2;
    const float4* B4 = (const float4*)B + ((size_t)wid * 8 + h) * 64 + q * 2;

    float4 a[8], bb[8];
    #pragma unroll
    for (int i = 0; i < 4; ++i) {                  // all loads up front (MLP)
        a[2*i]    = A4[i * 128];
        a[2*i+1]  = A4[i * 128 + 1];
        bb[2*i]   = B4[i * 128];
        bb[2*i+1] = B4[i * 128 + 1];
    }

    float ddAcc = 0.f;
    #pragma unroll
    for (int i = 0; i < 4; ++i) {
        float sa = dot8(a[2*i], a[2*i]) + dot8(a[2*i+1], a[2*i+1]);
        float sb = dot8(bb[2*i], bb[2*i]) + dot8(bb[2*i+1], bb[2*i+1]);
        float dd = dot8(a[2*i], bb[2*i]) + dot8(a[2*i+1], bb[2*i+1]);
        #pragma unroll
        for (int off = 1; off <= 16; off <<= 1) {
            sa += __shfl_xor(sa, off);
            sb += __shfl_xor(sb, off);
            dd += __shfl_xor(dd, off);
        }
        const float ia = 1.0f / fmaxf(sqrtf(sa), 1e-12f);
        const float ib = 1.0f / fmaxf(sqrtf(sb), 1e-12f);
        if (q == 0) ddAcc += dd * ia * ib * 10.0f;

        const int n0 = wid * 8 + i * 2 + h;
        const size_t chunk = (size_t)(n0 >> 11) * 65536
                           + (size_t)((n0 & 2047) >> 5) * 1024
                           + (q >> 1) * 64 + (q & 1) * 32 + (n0 & 31);
        E1f[chunk] = pack8(a[2*i], a[2*i+1], ia * SCALE_L2E);  // pre-scaled
        E2f[chunk] = pack8(bb[2*i], bb[2*i+1], ib);
    }

    #pragma unroll
    for (int off = 1; off <= 32; off <<= 1) ddAcc += __shfl_xor(ddAcc, off);
    __shared__ float part[4];
    if (l == 0) part[w] = ddAcc;
    __syncthreads();
    if (tid == 0) diagPart[blockIdx.x] = part[0] + part[1] + part[2] + part[3];
    if (blockIdx.x == 0 && tid == 0) { scalars[0] = 0.f; *counter = 0u; }
}

// ---------------------------------------------------------------------------
// Kernel 2: fused GEMM + exp + row/col partials. 512 blocks, 4 waves.
// Block: 256 rows x 512 cols; wave: 64 rows (af0/af1 in regs) x 512 cols.
// B staged 64-cols (32 KB) via global_load_lds, double-buffered; 8 barriers.
// Batch pinned to XCD: b = blockIdx&15 -> XCD = b&7; one XCD's blocks touch
// only 2 batches (4 MB E1f+E2f) = its own L2 -> staging & A-preload L2-local.
// ---------------------------------------------------------------------------
__global__ __launch_bounds__(256, 2) void gemm_kernel(
        const bf16x8* __restrict__ E1f, const uint4* __restrict__ E2f,
        float* __restrict__ colPart, float* __restrict__ rowPart) {
    __shared__ bf16x8 Bbuf[2][2048];   // 2 x 32 KB (64 cols each)
    __shared__ float colLDS[2048];     // 4 per-wave slices of 512

    const int tid = threadIdx.x, w = tid >> 6, l = tid & 63;
    const int b = blockIdx.x & 15;             // XCD = b&7 (L2 pinning)
    const int ct = (blockIdx.x >> 4) & 3, rt = blockIdx.x >> 6;

    for (int i = l; i < 512; i += 64) colLDS[w * 512 + i] = 0.f;

    const uint4* Bb = E2f + (size_t)b * 65536 + (size_t)ct * 16384 + l;

    // stage 64-col group sg into Bbuf[buf]; wave w covers 8 chunk-rows
    auto stage = [&](int buf, int sg) {
        const uint4* src = Bb + (size_t)sg * 2048 + (w * 8) * 64;
        #pragma unroll
        for (int j = 0; j < 8; ++j)
            async_copy16(src + j * 64, &Bbuf[buf][(w * 8 + j) * 64]);
    };

    stage(0, 0);   // DMA queued first; A-loads land behind it

    // A fragments: two 32-row tiles (fragment-major, coalesced 1KB loads)
    const bf16x8* Af0 = E1f + (size_t)b * 65536 + (size_t)(rt * 8 + w * 2) * 1024 + l;
    const bf16x8* Af1 = Af0 + 1024;
    bf16x8 af0[16], af1[16];
    #pragma unroll
    for (int kt = 0; kt < 16; ++kt) { af0[kt] = Af0[kt * 64]; af1[kt] = Af1[kt * 64]; }

    float rowAcc0[16], rowAcc1[16];
    #pragma unroll
    for (int r = 0; r < 16; ++r) { rowAcc0[r] = 0.f; rowAcc1[r] = 0.f; }

    __syncthreads();   // stage(0) + A-frags complete

    for (int sg = 0; sg < 8; ++sg) {
        if (sg < 7) stage((sg + 1) & 1, sg + 1);

        const bf16x8* Bf = Bbuf[sg & 1];
        for (int half = 0; half < 2; ++half) {
            f32x16 acc0, acc1;
            #pragma unroll
            for (int r = 0; r < 16; ++r) { acc0[r] = 0.f; acc1[r] = 0.f; }

            #pragma unroll
            for (int kt = 0; kt < 16; ++kt) {
                bf16x8 bfrag = Bf[half * 1024 + kt * 64 + l];
                acc0 = __builtin_amdgcn_mfma_f32_32x32x16_bf16(af0[kt], bfrag, acc0, 0, 0, 0);
                acc1 = __builtin_amdgcn_mfma_f32_32x32x16_bf16(af1[kt], bfrag, acc1, 0, 0, 0);
            }

            // epilogue: A pre-scaled -> e = exp2(acc - 10*log2e)
            float p = 0.f;
            #pragma unroll
            for (int r = 0; r < 16; ++r) {
                float e0 = exp2f(acc0[r] - SCALE_L2E);
                float e1 = exp2f(acc1[r] - SCALE_L2E);
                rowAcc0[r] += e0;
                rowAcc1[r] += e1;
                p += e0 + e1;
            }
            p += __shfl_xor(p, 32);                 // fold 16-row halves
            if (l < 32) colLDS[w * 512 + (sg * 2 + half) * 32 + l] += p;
        }
        __syncthreads();
    }

    // row sums: reduce across 32 column-lanes
    #pragma unroll
    for (int r = 0; r < 16; ++r) {
        #pragma unroll
        for (int off = 1; off <= 16; off <<= 1) {
            rowAcc0[r] += __shfl_xor(rowAcc0[r], off);
            rowAcc1[r] += __shfl_xor(rowAcc1[r], off);
        }
    }
    if ((l & 31) == 0) {
        // C/D layout: row = (r&3) + 8*(r>>2) + 4*(lane>>5); plain stores
        float* rs = rowPart + (size_t)(b * 4 + ct) * 2048 + rt * 256 + w * 64 + 4 * (l >> 5);
        #pragma unroll
        for (int r = 0; r < 16; ++r) {
            const int rl = (r & 3) + 8 * (r >> 2);
            rs[rl]      = rowAcc0[r];
            rs[rl + 32] = rowAcc1[r];
        }
    }

    __syncthreads();   // before cross-wave colLDS fold
    float* gcol = colPart + (size_t)((b * 4 + ct) * 8 + rt) * 512;
    for (int i = tid; i < 512; i += 256)
        gcol[i] = colLDS[i] + colLDS[512 + i] + colLDS[1024 + i] + colLDS[1536 + i];
}

// ---------------------------------------------------------------------------
// Kernel 3: fold partials, sum logs, last block finalizes.
// 64 blocks x 256. Block: 512 cols (8 rt-partials) + 512 rows (4 ct-partials).
// ---------------------------------------------------------------------------
__global__ __launch_bounds__(256) void fin_kernel(
        const float* __restrict__ colPart, const float* __restrict__ rowPart,
        const float* __restrict__ diagPart, float* __restrict__ scalars,
        unsigned int* __restrict__ counter, float* __restrict__ out) {
    const int tid = threadIdx.x;
    float s = 0.f;
    #pragma unroll
    for (int k = 0; k < 2; ++k) {
        const int g = blockIdx.x * 512 + k * 256 + tid;
        // column g: b = g>>11, ct = (g>>9)&3, c = g&511
        const float* cp = colPart + (size_t)(((g >> 11) * 4 + ((g >> 9) & 3)) * 8) * 512 + (g & 511);
        float cs = 0.f;
        #pragma unroll
        for (int rt = 0; rt < 8; ++rt) cs += cp[rt * 512];
        // row g: b = g>>11, r = g&2047
        const float* rp = rowPart + (size_t)(g >> 11) * 4 * 2048 + (g & 2047);
        float rsum = rp[0] + rp[2048] + rp[4096] + rp[6144];
        s += logf(cs) + logf(rsum);
    }
    #pragma unroll
    for (int off = 1; off <= 32; off <<= 1) s += __shfl_xor(s, off);
    __shared__ float part[4];
    __shared__ unsigned int lastFlag;
    if ((tid & 63) == 0) part[tid >> 6] = s;
    __syncthreads();
    if (tid == 0) {
        atomicAdd(&scalars[0], part[0] + part[1] + part[2] + part[3]);
        __threadfence();
        lastFlag = (atomicAdd(counter, 1u) == 63u) ? 1u : 0u;
    }
    __syncthreads();
    if (lastFlag) {
        float d = diagPart[tid] + diagPart[tid + 256]
                + diagPart[tid + 512] + diagPart[tid + 768];
        #pragma unroll
        for (int off = 1; off <= 32; off <<= 1) d += __shfl_xor(d, off);
        if ((tid & 63) == 0) part[tid >> 6] = d;
        __syncthreads();
        if (tid == 0) {
            const float diag = part[0] + part[1] + part[2] + part[3];
            const float logSum = atomicAdd(&scalars[0], 0.f);  // coherent read
            out[0] = (logSum - 2.0f * diag) / (float)NTOT + 20.0f;
        }
    }
}

// ---------------------------------------------------------------------------
extern "C" void kernel_launch(void* const* d_in, const int* in_sizes, int n_in,
                              void* d_out, int out_size, void* d_ws, size_t ws_size,
                              hipStream_t stream) {
    const float* A = (const float*)d_in[0];
    const float* B = (const float*)d_in[1];

    char* w = (char*)d_ws;
    uint4* E1f = (uint4*)w;                                    // 16 MB
    uint4* E2f = (uint4*)(w + (size_t)16 * 1024 * 1024);       // 16 MB
    float* colPart = (float*)(w + (size_t)32 * 1024 * 1024);   // 262144 f (1 MB)
    float* rowPart = colPart + 262144;                         // 131072 f (0.5 MB)
    float* diagPart = rowPart + 131072;                        // 1024 f
    float* scalars = diagPart + 1024;                          // [logSum]
    unsigned int* counter = (unsigned int*)(scalars + 1);

    hipLaunchKernelGGL(nrm_kernel, dim3(1024), dim3(256), 0, stream,
                       A, B, E1f, E2f, diagPart, scalars, counter);
    hipLaunchKernelGGL(gemm_kernel, dim3(512), dim3(256), 0, stream,
                       (const bf16x8*)E1f, (const uint4*)E2f, colPart, rowPart);
    hipLaunchKernelGGL(fin_kernel, dim3(64), dim3(256), 0, stream,
                       colPart, rowPart, diagPart, scalars, counter, (float*)d_out);
}